// Round 1
// baseline (546.418 us; speedup 1.0000x reference)
//
#include <hip/hip_runtime.h>
#include <cmath>

// CausalSelfAttention fused pipeline, MI355X/gfx950.
// R10: attn_fwd restructured — K fragments read DIRECT from global (the
// 16x16x32 B-frag layout is an identity copy of row-major K, so k_lds was a
// pure LDS-bandwidth tax), k_lds removed, p_lds pad 136->72 (2-way, free),
// blocks un-paired (1024 single-qsub blocks, big-first for LPT balance)
// -> 4 blocks/CU residency. GEMMs unchanged from R9.

#define S_LEN 2048
#define DMODEL 2048
#define NH 16
#define NKV 4
#define HD 128

#define NEG_SENT -1.0e30f
#define QK_SCALE 0.08838834764831845f  // 1/sqrt(128), folded into Q

typedef _Float16 f16x8 __attribute__((ext_vector_type(8)));
typedef float f32x4 __attribute__((ext_vector_type(4)));

static __device__ __forceinline__ short f2h(float f) {
  _Float16 h = (_Float16)f;
  return *(short*)&h;
}
static __device__ __forceinline__ float h2f(short s) {
  _Float16 h = *(_Float16*)&s;
  return (float)h;
}

// async global->LDS, 16B per lane; lds dst = wave-uniform base + lane*16.
static __device__ __forceinline__ void stage16(const short* g, short* ldsbase) {
  __builtin_amdgcn_global_load_lds(
      (const __attribute__((address_space(1))) void*)g,
      (__attribute__((address_space(3))) void*)ldsbase, 16, 0, 0);
}

// ---------------------------------------------------------------------------
// fp32 -> fp16 elementwise convert (n divisible by 4).
// ---------------------------------------------------------------------------
__global__ __launch_bounds__(256) void f32_to_f16(const float* __restrict__ src,
                                                  short* __restrict__ dst, int n) {
  int i = (blockIdx.x * 256 + threadIdx.x) * 4;
  if (i < n) {
    float4 v = *reinterpret_cast<const float4*>(src + i);
    short4 o;
    o.x = f2h(v.x); o.y = f2h(v.y); o.z = f2h(v.z); o.w = f2h(v.w);
    *reinterpret_cast<short4*>(dst + i) = o;
  }
}

// ---------------------------------------------------------------------------
// GEMM core: C[M,N] = A[M,K] @ W[N,K]^T, fp16 in, fp32 accum.
// 128x128 tile, BK=64. Staging via global_load_lds_dwordx4: wave w stages
// rows {w*8 + i*32 + lane/8}, cols (lane&7)*8 — LDS is unpadded [128][64]
// so lane l lands at base + l*16B exactly (required by the instruction).
// ---------------------------------------------------------------------------
template <bool F32OUT>
static __device__ __forceinline__ void gemm_core(const short* __restrict__ A,
                                                 const short* __restrict__ W,
                                                 void* __restrict__ Cv,
                                                 int N, int K, int bm, int bn) {
  __shared__ __align__(16) short As[128][64];
  __shared__ __align__(16) short Ws[128][64];
  const int tid = threadIdx.x;
  const int wave = tid >> 6, lane = tid & 63;
  const int quad = lane >> 4, l16 = lane & 15;
  const int wm = (wave >> 1) * 64, wn = (wave & 1) * 64;

  f32x4 acc[4][4];
#pragma unroll
  for (int i = 0; i < 4; i++)
#pragma unroll
    for (int j = 0; j < 4; j++) acc[i][j] = f32x4{0.f, 0.f, 0.f, 0.f};

  const int srow = wave * 8 + (lane >> 3);  // staging row (this lane)
  const int scol = (lane & 7) * 8;          // staging col

  for (int k0 = 0; k0 < K; k0 += 64) {
    __syncthreads();  // prior compute done before overwrite
#pragma unroll
    for (int i = 0; i < 4; i++) {
      stage16(A + (size_t)(bm + srow + i * 32) * K + k0 + scol,
              &As[wave * 8 + i * 32][0]);
      stage16(W + (size_t)(bn + srow + i * 32) * K + k0 + scol,
              &Ws[wave * 8 + i * 32][0]);
    }
    __syncthreads();  // staging visible (vmcnt drained by compiler)
#pragma unroll
    for (int kk = 0; kk < 64; kk += 32) {
      f16x8 af[4], bfr[4];
#pragma unroll
      for (int mi = 0; mi < 4; mi++)
        af[mi] = *reinterpret_cast<const f16x8*>(&As[wm + mi * 16 + l16][kk + quad * 8]);
#pragma unroll
      for (int ni = 0; ni < 4; ni++)
        bfr[ni] = *reinterpret_cast<const f16x8*>(&Ws[wn + ni * 16 + l16][kk + quad * 8]);
#pragma unroll
      for (int mi = 0; mi < 4; mi++)
#pragma unroll
        for (int ni = 0; ni < 4; ni++)
          acc[mi][ni] = __builtin_amdgcn_mfma_f32_16x16x32_f16(af[mi], bfr[ni], acc[mi][ni], 0, 0, 0);
    }
  }
  // C/D layout: row = quad*4 + r, col = l16
#pragma unroll
  for (int mi = 0; mi < 4; mi++)
#pragma unroll
    for (int ni = 0; ni < 4; ni++) {
      int gr = bm + wm + mi * 16 + quad * 4;
      int gc = bn + wn + ni * 16 + l16;
#pragma unroll
      for (int r = 0; r < 4; r++) {
        if (F32OUT)
          ((float*)Cv)[(size_t)(gr + r) * N + gc] = acc[mi][ni][r];
        else
          ((short*)Cv)[(size_t)(gr + r) * N + gc] = f2h(acc[mi][ni][r]);
      }
    }
}

template <bool F32OUT>
__global__ __launch_bounds__(256) void gemm_bt(const short* __restrict__ A,
                                               const short* __restrict__ W,
                                               void* __restrict__ Cv,
                                               int N, int K) {
  gemm_core<F32OUT>(A, W, Cv, N, K, blockIdx.x * 128, blockIdx.y * 128);
}

// K and V projections fused: blockIdx.z selects (W, C). Grid (32,4,2) = 256.
__global__ __launch_bounds__(256) void gemm_kv(const short* __restrict__ A,
                                               const short* __restrict__ W0,
                                               const short* __restrict__ W1,
                                               short* __restrict__ C0,
                                               short* __restrict__ C1,
                                               int N, int K) {
  const short* W = blockIdx.z ? W1 : W0;
  short* C = blockIdx.z ? C1 : C0;
  gemm_core<false>(A, W, (void*)C, N, K, blockIdx.x * 128, blockIdx.y * 128);
}

// ---------------------------------------------------------------------------
// Per-(token,head) RMSNorm + partial RoPE + optional gain, relayout to
// [b][head][s][128]. mode: 1=norm+rope(k), 2=norm+rope+gain*qk_scale(q).
// ---------------------------------------------------------------------------
__global__ __launch_bounds__(256) void postproc(const short* __restrict__ src,
                                                short* __restrict__ dst,
                                                const float* __restrict__ gain,
                                                int n_heads, int mode) {
  int gw = blockIdx.x * 4 + (threadIdx.x >> 6);
  int lane = threadIdx.x & 63;
  int head = gw % n_heads;
  int token = gw / n_heads;
  int s = token & (S_LEN - 1);
  int b = token >> 11;
  const short* sp = src + (size_t)token * (n_heads * HD) + head * HD;
  float v0 = h2f(sp[lane]);
  float v1 = h2f(sp[lane + 64]);
  float ss = v0 * v0 + v1 * v1;
#pragma unroll
  for (int off = 1; off < 64; off <<= 1) ss += __shfl_xor(ss, off, 64);
  float sc = rsqrtf(ss * (1.0f / 128.0f) + 1.1920929e-07f);
  v0 *= sc;
  v1 *= sc;
  int i = lane & 31;
  float inv = powf(10000.0f, -((float)(2 * i) * (1.0f / 64.0f)));
  float f = (float)s * inv;
  float cs, sn;
  sincosf(f, &sn, &cs);
  float partner = __shfl_xor(v0, 32, 64);
  v0 = (lane < 32) ? (v0 * cs + partner * sn) : (v0 * cs - partner * sn);
  if (mode == 2) {
    float g = gain[head] * QK_SCALE;  // fold 1/sqrt(d) into Q
    v0 *= g;
    v1 *= g;
  }
  short* dp = dst + ((size_t)(b * n_heads + head) * S_LEN + s) * HD;
  dp[lane] = f2h(v0);
  dp[lane + 64] = f2h(v1);
}

// ---------------------------------------------------------------------------
// Tiled transpose: vraw[token][512] -> vT[b][kv][dim128][seq2048].
// ---------------------------------------------------------------------------
__global__ __launch_bounds__(256) void v_transpose(const short* __restrict__ src,
                                                   short* __restrict__ dst) {
  __shared__ __align__(16) short t[64][72];
  const int tid = threadIdx.x;
  const int s0 = blockIdx.x * 64;
  const int d0 = blockIdx.y * 64;
#pragma unroll
  for (int i = 0; i < 2; i++) {
    int r = (tid >> 3) + i * 32;
    int c = (tid & 7) * 8;
    *reinterpret_cast<int4*>(&t[r][c]) =
        *reinterpret_cast<const int4*>(src + (size_t)(s0 + r) * 512 + d0 + c);
  }
  __syncthreads();
  const int b = s0 >> 11;
  const int sbase = s0 & (S_LEN - 1);
#pragma unroll
  for (int i = 0; i < 2; i++) {
    int dr = (tid >> 3) + i * 32;
    int sc8 = (tid & 7) * 8;
    int d = d0 + dr;
    int kv = d >> 7, dw = d & 127;
    short4 lo, hi;
    lo.x = t[sc8 + 0][dr]; lo.y = t[sc8 + 1][dr];
    lo.z = t[sc8 + 2][dr]; lo.w = t[sc8 + 3][dr];
    hi.x = t[sc8 + 4][dr]; hi.y = t[sc8 + 5][dr];
    hi.z = t[sc8 + 6][dr]; hi.w = t[sc8 + 7][dr];
    short* dp = dst + (((size_t)(b * NKV + kv) * HD + dw) * S_LEN) + sbase + sc8;
    *reinterpret_cast<short4*>(dp) = lo;
    *reinterpret_cast<short4*>(dp + 4) = hi;
  }
}

// ---------------------------------------------------------------------------
// Flash-style causal attention, R10.
// Block = 4 waves; wave = 16 queries; ONE qsub (64 queries) per block.
// Grid (32, 32) = 1024 blocks, qsub = 31 - blockIdx.x so the longest blocks
// dispatch first (LPT balance). K fragments are read directly from global
// (identity layout match with the 16x16x32 B-frag); the 16KB K tile is
// shared by the 4 lockstep waves through L1 and rides the vector-memory
// pipe, in parallel with the LDS pipe that feeds V and P. LDS = 29.9KB
// -> 4 blocks/CU with launch_bounds(256,4). Rowsum via ones-column MFMA;
// Q pre-scaled; fast-path masking; alpha-skip — all unchanged from R8/R9.
// ---------------------------------------------------------------------------
__global__ __launch_bounds__(256, 4) void attn_fwd(const short* __restrict__ qb,
                                                   const short* __restrict__ kb,
                                                   const short* __restrict__ vT,
                                                   short* __restrict__ out) {
  __shared__ __align__(16) short vt_lds[144][72];
  __shared__ __align__(16) short p_lds[4][16][72];

  const int tid = threadIdx.x, wave = tid >> 6, lane = tid & 63;
  const int quad = lane >> 4, l16 = lane & 15;
  const int bh = blockIdx.y;
  const int b = bh >> 4, h = bh & 15;
  const int kvh = h >> 2;
  const int qsub = 31 - blockIdx.x;  // 0..31, big-first

  const short* kptr = kb + ((size_t)(b * NKV + kvh) * S_LEN) * HD;
  const short* vtp  = vT + ((size_t)(b * NKV + kvh) * HD) * S_LEN;

  const int vr = (tid >> 3), vc = (tid & 7) * 8;

  // ones-column tile (rows 128..143) for the rowsum-via-MFMA trick
  {
    int r = 128 + (tid >> 4);
    int c = (tid & 15) * 4;
    short val = (r == 128) ? (short)0x3C00 : (short)0;
    short4 v4 = {val, val, val, val};
    *reinterpret_cast<short4*>(&vt_lds[r][c]) = v4;
  }

  const int q0 = qsub * 64 + wave * 16;
  const short* qptr = qb + ((size_t)(b * NH + h) * S_LEN + q0) * HD;
  // per-lane K fragment base: row l16, halves quad*8 (B-frag identity map)
  const short* kl = kptr + (size_t)l16 * HD + quad * 8;

  f16x8 qf[4];
#pragma unroll
  for (int st = 0; st < 4; st++)
    qf[st] = *reinterpret_cast<const f16x8*>(
        qptr + (size_t)l16 * HD + st * 32 + quad * 8);

  f32x4 o[9];
#pragma unroll
  for (int i = 0; i < 9; i++) o[i] = f32x4{0.f, 0.f, 0.f, 0.f};
  float m_i[4] = {NEG_SENT, NEG_SENT, NEG_SENT, NEG_SENT};

  const int ktiles = qsub + 1;
  for (int kt = 0; kt < ktiles; kt++) {
    const int kbase = kt * 64;
    __syncthreads();  // prior tile's V reads done before overwrite
#pragma unroll
    for (int i = 0; i < 4; i++)
      *reinterpret_cast<int4*>(&vt_lds[vr + i * 32][vc]) =
          *reinterpret_cast<const int4*>(vtp + (size_t)(vr + i * 32) * S_LEN + kbase + vc);
    __syncthreads();  // V staged (also covers ones-init on iter 0)

    // QK^T: K fragments direct from global (L1-resident across the 4 waves)
    f32x4 sc[4];
#pragma unroll
    for (int ct = 0; ct < 4; ct++) sc[ct] = f32x4{0.f, 0.f, 0.f, 0.f};
#pragma unroll
    for (int ct = 0; ct < 4; ct++) {
      const short* kp = kl + (size_t)(kbase + ct * 16) * HD;
#pragma unroll
      for (int st = 0; st < 4; st++) {
        f16x8 kf = *reinterpret_cast<const f16x8*>(kp + st * 32);
        sc[ct] = __builtin_amdgcn_mfma_f32_16x16x32_f16(qf[st], kf, sc[ct], 0, 0, 0);
      }
    }

    if (kbase + 63 > q0) {
#pragma unroll
      for (int ct = 0; ct < 4; ct++)
#pragma unroll
        for (int r = 0; r < 4; r++) {
          int qrow = q0 + quad * 4 + r;
          int col = kbase + ct * 16 + l16;
          sc[ct][r] = (col <= qrow) ? sc[ct][r] : NEG_SENT;
        }
    }

    float cand[4];
#pragma unroll
    for (int r = 0; r < 4; r++)
      cand[r] = fmaxf(fmaxf(sc[0][r], sc[1][r]), fmaxf(sc[2][r], sc[3][r]));
#pragma unroll
    for (int off = 1; off < 16; off <<= 1)
#pragma unroll
      for (int r = 0; r < 4; r++)
        cand[r] = fmaxf(cand[r], __shfl_xor(cand[r], off, 64));

    bool ch = (cand[0] > m_i[0]) | (cand[1] > m_i[1]) |
              (cand[2] > m_i[2]) | (cand[3] > m_i[3]);
    if (__any(ch)) {
      float alpha[4];
#pragma unroll
      for (int r = 0; r < 4; r++) {
        float mn = fmaxf(m_i[r], cand[r]);
        alpha[r] = __expf(m_i[r] - mn);
        m_i[r] = mn;
      }
#pragma unroll
      for (int nt = 0; nt < 9; nt++)
#pragma unroll
        for (int r = 0; r < 4; r++) o[nt][r] *= alpha[r];
    }

#pragma unroll
    for (int ct = 0; ct < 4; ct++)
#pragma unroll
      for (int r = 0; r < 4; r++) {
        float p = __expf(sc[ct][r] - m_i[r]);
        p_lds[wave][quad * 4 + r][ct * 16 + l16] = f2h(p);
      }

    f16x8 pf0 = *reinterpret_cast<const f16x8*>(&p_lds[wave][l16][quad * 8]);
    f16x8 pf1 = *reinterpret_cast<const f16x8*>(&p_lds[wave][l16][32 + quad * 8]);
#pragma unroll
    for (int nt = 0; nt < 9; nt++) {
      f16x8 vf0 = *reinterpret_cast<const f16x8*>(&vt_lds[nt * 16 + l16][quad * 8]);
      f16x8 vf1 = *reinterpret_cast<const f16x8*>(&vt_lds[nt * 16 + l16][32 + quad * 8]);
      o[nt] = __builtin_amdgcn_mfma_f32_16x16x32_f16(pf0, vf0, o[nt], 0, 0, 0);
      o[nt] = __builtin_amdgcn_mfma_f32_16x16x32_f16(pf1, vf1, o[nt], 0, 0, 0);
    }
  }

  float inv_l[4];
#pragma unroll
  for (int r = 0; r < 4; r++) {
    float l = __shfl(o[8][r], lane & 48, 64);
    inv_l[r] = 1.0f / fmaxf(l, 1e-20f);
  }
#pragma unroll
  for (int nt = 0; nt < 8; nt++)
#pragma unroll
    for (int r = 0; r < 4; r++) {
      int srow = q0 + quad * 4 + r;
      int dcol = nt * 16 + l16;
      out[((size_t)(b * S_LEN + srow)) * DMODEL + h * HD + dcol] =
          f2h(o[nt][r] * inv_l[r]);
    }
}

extern "C" void kernel_launch(void* const* d_in, const int* in_sizes, int n_in,
                              void* d_out, int out_size, void* d_ws, size_t ws_size,
                              hipStream_t stream) {
  const float* x      = (const float*)d_in[0];
  const float* q_w    = (const float*)d_in[1];
  const float* k_w    = (const float*)d_in[2];
  const float* v_w    = (const float*)d_in[3];
  const float* out_w  = (const float*)d_in[4];
  const float* q_gain = (const float*)d_in[5];
  float* out = (float*)d_out;

  const int BS = 2 * S_LEN;  // 4096 tokens
  short* xb   = (short*)d_ws;                    // 8M  (16MB)
  short* wqb  = xb   + (size_t)8 * 1024 * 1024;  // 4M
  short* wkb  = wqb  + (size_t)4 * 1024 * 1024;  // 1M
  short* wvb  = wkb  + (size_t)1 * 1024 * 1024;  // 1M
  short* wob  = wvb  + (size_t)1 * 1024 * 1024;  // 4M
  short* qraw = wob  + (size_t)4 * 1024 * 1024;  // 8M
  short* kraw = qraw + (size_t)8 * 1024 * 1024;  // 2M
  short* vraw = kraw + (size_t)2 * 1024 * 1024;  // 2M (token-major V)
  short* qbuf = vraw + (size_t)2 * 1024 * 1024;  // 8M
  short* kbuf = qbuf + (size_t)8 * 1024 * 1024;  // 2M
  short* vT   = kbuf + (size_t)2 * 1024 * 1024;  // 2M ([b][kv][dim][seq])
  short* attn = qraw;                            // alias

  dim3 blk(256);
  f32_to_f16<<<8192, blk, 0, stream>>>(x, xb, BS * DMODEL);
  f32_to_f16<<<4096, blk, 0, stream>>>(q_w, wqb, DMODEL * DMODEL);
  f32_to_f16<<<1024, blk, 0, stream>>>(k_w, wkb, 512 * DMODEL);
  f32_to_f16<<<1024, blk, 0, stream>>>(v_w, wvb, 512 * DMODEL);
  f32_to_f16<<<4096, blk, 0, stream>>>(out_w, wob, DMODEL * DMODEL);

  gemm_bt<false><<<dim3(32, 16), blk, 0, stream>>>(xb, wqb, qraw, 2048, 2048);
  gemm_kv<<<dim3(32, 4, 2), blk, 0, stream>>>(xb, wkb, wvb, kraw, vraw, 512, 2048);

  postproc<<<dim3((BS * NH) / 4), blk, 0, stream>>>(qraw, qbuf, q_gain, NH, 2);
  postproc<<<dim3((BS * NKV) / 4), blk, 0, stream>>>(kraw, kbuf, q_gain, NKV, 1);
  v_transpose<<<dim3(BS / 64, 8), blk, 0, stream>>>(vraw, vT);

  attn_fwd<<<dim3(32, 2 * NH), blk, 0, stream>>>(qbuf, kbuf, vT, attn);

  gemm_bt<true><<<dim3(32, 16), blk, 0, stream>>>(attn, wob, out, 2048, 2048);
}

// Round 2
// 448.026 us; speedup vs baseline: 1.2196x; 1.2196x over previous
//
#include <hip/hip_runtime.h>
#include <cmath>

// CausalSelfAttention fused pipeline, MI355X/gfx950.
// R11: revert R10's direct-global K reads (latency-bound regression: every
// QK MFMA waited on an unprefetched VMEM gather; L1 thrashed). Restore R9's
// k_lds/vt_lds staged attention, keep the two safe deltas: p_lds pad 136->72
// (2-way = free) => LDS 47.3KB => 3 blocks/CU, and un-paired 1024 blocks
// (big-first LPT) so the third block slot fills. GEMMs unchanged from R9.

#define S_LEN 2048
#define DMODEL 2048
#define NH 16
#define NKV 4
#define HD 128

#define NEG_SENT -1.0e30f
#define QK_SCALE 0.08838834764831845f  // 1/sqrt(128), folded into Q

typedef _Float16 f16x8 __attribute__((ext_vector_type(8)));
typedef float f32x4 __attribute__((ext_vector_type(4)));

static __device__ __forceinline__ short f2h(float f) {
  _Float16 h = (_Float16)f;
  return *(short*)&h;
}
static __device__ __forceinline__ float h2f(short s) {
  _Float16 h = *(_Float16*)&s;
  return (float)h;
}

// async global->LDS, 16B per lane; lds dst = wave-uniform base + lane*16.
static __device__ __forceinline__ void stage16(const short* g, short* ldsbase) {
  __builtin_amdgcn_global_load_lds(
      (const __attribute__((address_space(1))) void*)g,
      (__attribute__((address_space(3))) void*)ldsbase, 16, 0, 0);
}

// ---------------------------------------------------------------------------
// fp32 -> fp16 elementwise convert (n divisible by 4).
// ---------------------------------------------------------------------------
__global__ __launch_bounds__(256) void f32_to_f16(const float* __restrict__ src,
                                                  short* __restrict__ dst, int n) {
  int i = (blockIdx.x * 256 + threadIdx.x) * 4;
  if (i < n) {
    float4 v = *reinterpret_cast<const float4*>(src + i);
    short4 o;
    o.x = f2h(v.x); o.y = f2h(v.y); o.z = f2h(v.z); o.w = f2h(v.w);
    *reinterpret_cast<short4*>(dst + i) = o;
  }
}

// ---------------------------------------------------------------------------
// GEMM core: C[M,N] = A[M,K] @ W[N,K]^T, fp16 in, fp32 accum.
// 128x128 tile, BK=64. Staging via global_load_lds_dwordx4: wave w stages
// rows {w*8 + i*32 + lane/8}, cols (lane&7)*8 — LDS is unpadded [128][64]
// so lane l lands at base + l*16B exactly (required by the instruction).
// ---------------------------------------------------------------------------
template <bool F32OUT>
static __device__ __forceinline__ void gemm_core(const short* __restrict__ A,
                                                 const short* __restrict__ W,
                                                 void* __restrict__ Cv,
                                                 int N, int K, int bm, int bn) {
  __shared__ __align__(16) short As[128][64];
  __shared__ __align__(16) short Ws[128][64];
  const int tid = threadIdx.x;
  const int wave = tid >> 6, lane = tid & 63;
  const int quad = lane >> 4, l16 = lane & 15;
  const int wm = (wave >> 1) * 64, wn = (wave & 1) * 64;

  f32x4 acc[4][4];
#pragma unroll
  for (int i = 0; i < 4; i++)
#pragma unroll
    for (int j = 0; j < 4; j++) acc[i][j] = f32x4{0.f, 0.f, 0.f, 0.f};

  const int srow = wave * 8 + (lane >> 3);  // staging row (this lane)
  const int scol = (lane & 7) * 8;          // staging col

  for (int k0 = 0; k0 < K; k0 += 64) {
    __syncthreads();  // prior compute done before overwrite
#pragma unroll
    for (int i = 0; i < 4; i++) {
      stage16(A + (size_t)(bm + srow + i * 32) * K + k0 + scol,
              &As[wave * 8 + i * 32][0]);
      stage16(W + (size_t)(bn + srow + i * 32) * K + k0 + scol,
              &Ws[wave * 8 + i * 32][0]);
    }
    __syncthreads();  // staging visible (vmcnt drained by compiler)
#pragma unroll
    for (int kk = 0; kk < 64; kk += 32) {
      f16x8 af[4], bfr[4];
#pragma unroll
      for (int mi = 0; mi < 4; mi++)
        af[mi] = *reinterpret_cast<const f16x8*>(&As[wm + mi * 16 + l16][kk + quad * 8]);
#pragma unroll
      for (int ni = 0; ni < 4; ni++)
        bfr[ni] = *reinterpret_cast<const f16x8*>(&Ws[wn + ni * 16 + l16][kk + quad * 8]);
#pragma unroll
      for (int mi = 0; mi < 4; mi++)
#pragma unroll
        for (int ni = 0; ni < 4; ni++)
          acc[mi][ni] = __builtin_amdgcn_mfma_f32_16x16x32_f16(af[mi], bfr[ni], acc[mi][ni], 0, 0, 0);
    }
  }
  // C/D layout: row = quad*4 + r, col = l16
#pragma unroll
  for (int mi = 0; mi < 4; mi++)
#pragma unroll
    for (int ni = 0; ni < 4; ni++) {
      int gr = bm + wm + mi * 16 + quad * 4;
      int gc = bn + wn + ni * 16 + l16;
#pragma unroll
      for (int r = 0; r < 4; r++) {
        if (F32OUT)
          ((float*)Cv)[(size_t)(gr + r) * N + gc] = acc[mi][ni][r];
        else
          ((short*)Cv)[(size_t)(gr + r) * N + gc] = f2h(acc[mi][ni][r]);
      }
    }
}

template <bool F32OUT>
__global__ __launch_bounds__(256) void gemm_bt(const short* __restrict__ A,
                                               const short* __restrict__ W,
                                               void* __restrict__ Cv,
                                               int N, int K) {
  gemm_core<F32OUT>(A, W, Cv, N, K, blockIdx.x * 128, blockIdx.y * 128);
}

// K and V projections fused: blockIdx.z selects (W, C). Grid (32,4,2) = 256.
__global__ __launch_bounds__(256) void gemm_kv(const short* __restrict__ A,
                                               const short* __restrict__ W0,
                                               const short* __restrict__ W1,
                                               short* __restrict__ C0,
                                               short* __restrict__ C1,
                                               int N, int K) {
  const short* W = blockIdx.z ? W1 : W0;
  short* C = blockIdx.z ? C1 : C0;
  gemm_core<false>(A, W, (void*)C, N, K, blockIdx.x * 128, blockIdx.y * 128);
}

// ---------------------------------------------------------------------------
// Per-(token,head) RMSNorm + partial RoPE + optional gain, relayout to
// [b][head][s][128]. mode: 1=norm+rope(k), 2=norm+rope+gain*qk_scale(q).
// ---------------------------------------------------------------------------
__global__ __launch_bounds__(256) void postproc(const short* __restrict__ src,
                                                short* __restrict__ dst,
                                                const float* __restrict__ gain,
                                                int n_heads, int mode) {
  int gw = blockIdx.x * 4 + (threadIdx.x >> 6);
  int lane = threadIdx.x & 63;
  int head = gw % n_heads;
  int token = gw / n_heads;
  int s = token & (S_LEN - 1);
  int b = token >> 11;
  const short* sp = src + (size_t)token * (n_heads * HD) + head * HD;
  float v0 = h2f(sp[lane]);
  float v1 = h2f(sp[lane + 64]);
  float ss = v0 * v0 + v1 * v1;
#pragma unroll
  for (int off = 1; off < 64; off <<= 1) ss += __shfl_xor(ss, off, 64);
  float sc = rsqrtf(ss * (1.0f / 128.0f) + 1.1920929e-07f);
  v0 *= sc;
  v1 *= sc;
  int i = lane & 31;
  float inv = powf(10000.0f, -((float)(2 * i) * (1.0f / 64.0f)));
  float f = (float)s * inv;
  float cs, sn;
  sincosf(f, &sn, &cs);
  float partner = __shfl_xor(v0, 32, 64);
  v0 = (lane < 32) ? (v0 * cs + partner * sn) : (v0 * cs - partner * sn);
  if (mode == 2) {
    float g = gain[head] * QK_SCALE;  // fold 1/sqrt(d) into Q
    v0 *= g;
    v1 *= g;
  }
  short* dp = dst + ((size_t)(b * n_heads + head) * S_LEN + s) * HD;
  dp[lane] = f2h(v0);
  dp[lane + 64] = f2h(v1);
}

// ---------------------------------------------------------------------------
// Tiled transpose: vraw[token][512] -> vT[b][kv][dim128][seq2048].
// ---------------------------------------------------------------------------
__global__ __launch_bounds__(256) void v_transpose(const short* __restrict__ src,
                                                   short* __restrict__ dst) {
  __shared__ __align__(16) short t[64][72];
  const int tid = threadIdx.x;
  const int s0 = blockIdx.x * 64;
  const int d0 = blockIdx.y * 64;
#pragma unroll
  for (int i = 0; i < 2; i++) {
    int r = (tid >> 3) + i * 32;
    int c = (tid & 7) * 8;
    *reinterpret_cast<int4*>(&t[r][c]) =
        *reinterpret_cast<const int4*>(src + (size_t)(s0 + r) * 512 + d0 + c);
  }
  __syncthreads();
  const int b = s0 >> 11;
  const int sbase = s0 & (S_LEN - 1);
#pragma unroll
  for (int i = 0; i < 2; i++) {
    int dr = (tid >> 3) + i * 32;
    int sc8 = (tid & 7) * 8;
    int d = d0 + dr;
    int kv = d >> 7, dw = d & 127;
    short4 lo, hi;
    lo.x = t[sc8 + 0][dr]; lo.y = t[sc8 + 1][dr];
    lo.z = t[sc8 + 2][dr]; lo.w = t[sc8 + 3][dr];
    hi.x = t[sc8 + 4][dr]; hi.y = t[sc8 + 5][dr];
    hi.z = t[sc8 + 6][dr]; hi.w = t[sc8 + 7][dr];
    short* dp = dst + (((size_t)(b * NKV + kv) * HD + dw) * S_LEN) + sbase + sc8;
    *reinterpret_cast<short4*>(dp) = lo;
    *reinterpret_cast<short4*>(dp + 4) = hi;
  }
}

// ---------------------------------------------------------------------------
// Flash-style causal attention, R11 (= R9 staging structure, un-paired).
// Block = 4 waves; wave = 16 queries; ONE qsub (64 queries) per block.
// Grid (32, 32) = 1024 blocks, qsub = 31 - blockIdx.x (big-first, LPT).
// K and V staged in LDS per tile (prefetch + 4-wave reuse; R10 showed
// direct-global K is latency-bound). p_lds pad 72 (row stride 36 words
// == 4 mod 32 -> 2-way aliasing, free) => LDS 47.3KB => 3 blocks/CU.
// Rowsum via ones-column MFMA; Q pre-scaled; fast-path masking; alpha-skip.
// ---------------------------------------------------------------------------
__global__ __launch_bounds__(256, 3) void attn_fwd(const short* __restrict__ qb,
                                                   const short* __restrict__ kb,
                                                   const short* __restrict__ vT,
                                                   short* __restrict__ out) {
  __shared__ __align__(16) short k_lds[64][136];
  __shared__ __align__(16) short vt_lds[144][72];
  __shared__ __align__(16) short p_lds[4][16][72];

  const int tid = threadIdx.x, wave = tid >> 6, lane = tid & 63;
  const int quad = lane >> 4, l16 = lane & 15;
  const int bh = blockIdx.y;
  const int b = bh >> 4, h = bh & 15;
  const int kvh = h >> 2;
  const int qsub = 31 - blockIdx.x;  // 0..31, big-first

  const short* kptr = kb + ((size_t)(b * NKV + kvh) * S_LEN) * HD;
  const short* vtp  = vT + ((size_t)(b * NKV + kvh) * HD) * S_LEN;

  const int kr = (tid >> 4), kc = (tid & 15) * 8;
  const int vr = (tid >> 3), vc = (tid & 7) * 8;

  // ones-column tile (rows 128..143) for the rowsum-via-MFMA trick
  {
    int r = 128 + (tid >> 4);
    int c = (tid & 15) * 4;
    short val = (r == 128) ? (short)0x3C00 : (short)0;
    short4 v4 = {val, val, val, val};
    *reinterpret_cast<short4*>(&vt_lds[r][c]) = v4;
  }

  const int q0 = qsub * 64 + wave * 16;
  const short* qptr = qb + ((size_t)(b * NH + h) * S_LEN + q0) * HD;

  f16x8 qf[4];
#pragma unroll
  for (int st = 0; st < 4; st++)
    qf[st] = *reinterpret_cast<const f16x8*>(
        qptr + (size_t)l16 * HD + st * 32 + quad * 8);

  f32x4 o[9];
#pragma unroll
  for (int i = 0; i < 9; i++) o[i] = f32x4{0.f, 0.f, 0.f, 0.f};
  float m_i[4] = {NEG_SENT, NEG_SENT, NEG_SENT, NEG_SENT};

  const int ktiles = qsub + 1;
  for (int kt = 0; kt < ktiles; kt++) {
    const int kbase = kt * 64;
    __syncthreads();  // prior tile's reads done before overwrite
#pragma unroll
    for (int i = 0; i < 4; i++)
      *reinterpret_cast<int4*>(&k_lds[kr + i * 16][kc]) =
          *reinterpret_cast<const int4*>(kptr + (size_t)(kbase + kr + i * 16) * HD + kc);
#pragma unroll
    for (int i = 0; i < 4; i++)
      *reinterpret_cast<int4*>(&vt_lds[vr + i * 32][vc]) =
          *reinterpret_cast<const int4*>(vtp + (size_t)(vr + i * 32) * S_LEN + kbase + vc);
    __syncthreads();  // staging visible (also covers ones-init on iter 0)

    f32x4 sc[4];
#pragma unroll
    for (int ct = 0; ct < 4; ct++) sc[ct] = f32x4{0.f, 0.f, 0.f, 0.f};
#pragma unroll
    for (int ct = 0; ct < 4; ct++) {
#pragma unroll
      for (int st = 0; st < 4; st++) {
        f16x8 kf = *reinterpret_cast<const f16x8*>(&k_lds[ct * 16 + l16][st * 32 + quad * 8]);
        sc[ct] = __builtin_amdgcn_mfma_f32_16x16x32_f16(qf[st], kf, sc[ct], 0, 0, 0);
      }
    }

    if (kbase + 63 > q0) {
#pragma unroll
      for (int ct = 0; ct < 4; ct++)
#pragma unroll
        for (int r = 0; r < 4; r++) {
          int qrow = q0 + quad * 4 + r;
          int col = kbase + ct * 16 + l16;
          sc[ct][r] = (col <= qrow) ? sc[ct][r] : NEG_SENT;
        }
    }

    float cand[4];
#pragma unroll
    for (int r = 0; r < 4; r++)
      cand[r] = fmaxf(fmaxf(sc[0][r], sc[1][r]), fmaxf(sc[2][r], sc[3][r]));
#pragma unroll
    for (int off = 1; off < 16; off <<= 1)
#pragma unroll
      for (int r = 0; r < 4; r++)
        cand[r] = fmaxf(cand[r], __shfl_xor(cand[r], off, 64));

    bool ch = (cand[0] > m_i[0]) | (cand[1] > m_i[1]) |
              (cand[2] > m_i[2]) | (cand[3] > m_i[3]);
    if (__any(ch)) {
      float alpha[4];
#pragma unroll
      for (int r = 0; r < 4; r++) {
        float mn = fmaxf(m_i[r], cand[r]);
        alpha[r] = __expf(m_i[r] - mn);
        m_i[r] = mn;
      }
#pragma unroll
      for (int nt = 0; nt < 9; nt++)
#pragma unroll
        for (int r = 0; r < 4; r++) o[nt][r] *= alpha[r];
    }

#pragma unroll
    for (int ct = 0; ct < 4; ct++)
#pragma unroll
      for (int r = 0; r < 4; r++) {
        float p = __expf(sc[ct][r] - m_i[r]);
        p_lds[wave][quad * 4 + r][ct * 16 + l16] = f2h(p);
      }

    f16x8 pf0 = *reinterpret_cast<const f16x8*>(&p_lds[wave][l16][quad * 8]);
    f16x8 pf1 = *reinterpret_cast<const f16x8*>(&p_lds[wave][l16][32 + quad * 8]);
#pragma unroll
    for (int nt = 0; nt < 9; nt++) {
      f16x8 vf0 = *reinterpret_cast<const f16x8*>(&vt_lds[nt * 16 + l16][quad * 8]);
      f16x8 vf1 = *reinterpret_cast<const f16x8*>(&vt_lds[nt * 16 + l16][32 + quad * 8]);
      o[nt] = __builtin_amdgcn_mfma_f32_16x16x32_f16(pf0, vf0, o[nt], 0, 0, 0);
      o[nt] = __builtin_amdgcn_mfma_f32_16x16x32_f16(pf1, vf1, o[nt], 0, 0, 0);
    }
  }

  float inv_l[4];
#pragma unroll
  for (int r = 0; r < 4; r++) {
    float l = __shfl(o[8][r], lane & 48, 64);
    inv_l[r] = 1.0f / fmaxf(l, 1e-20f);
  }
#pragma unroll
  for (int nt = 0; nt < 8; nt++)
#pragma unroll
    for (int r = 0; r < 4; r++) {
      int srow = q0 + quad * 4 + r;
      int dcol = nt * 16 + l16;
      out[((size_t)(b * S_LEN + srow)) * DMODEL + h * HD + dcol] =
          f2h(o[nt][r] * inv_l[r]);
    }
}

extern "C" void kernel_launch(void* const* d_in, const int* in_sizes, int n_in,
                              void* d_out, int out_size, void* d_ws, size_t ws_size,
                              hipStream_t stream) {
  const float* x      = (const float*)d_in[0];
  const float* q_w    = (const float*)d_in[1];
  const float* k_w    = (const float*)d_in[2];
  const float* v_w    = (const float*)d_in[3];
  const float* out_w  = (const float*)d_in[4];
  const float* q_gain = (const float*)d_in[5];
  float* out = (float*)d_out;

  const int BS = 2 * S_LEN;  // 4096 tokens
  short* xb   = (short*)d_ws;                    // 8M  (16MB)
  short* wqb  = xb   + (size_t)8 * 1024 * 1024;  // 4M
  short* wkb  = wqb  + (size_t)4 * 1024 * 1024;  // 1M
  short* wvb  = wkb  + (size_t)1 * 1024 * 1024;  // 1M
  short* wob  = wvb  + (size_t)1 * 1024 * 1024;  // 4M
  short* qraw = wob  + (size_t)4 * 1024 * 1024;  // 8M
  short* kraw = qraw + (size_t)8 * 1024 * 1024;  // 2M
  short* vraw = kraw + (size_t)2 * 1024 * 1024;  // 2M (token-major V)
  short* qbuf = vraw + (size_t)2 * 1024 * 1024;  // 8M
  short* kbuf = qbuf + (size_t)8 * 1024 * 1024;  // 2M
  short* vT   = kbuf + (size_t)2 * 1024 * 1024;  // 2M ([b][kv][dim][seq])
  short* attn = qraw;                            // alias

  dim3 blk(256);
  f32_to_f16<<<8192, blk, 0, stream>>>(x, xb, BS * DMODEL);
  f32_to_f16<<<4096, blk, 0, stream>>>(q_w, wqb, DMODEL * DMODEL);
  f32_to_f16<<<1024, blk, 0, stream>>>(k_w, wkb, 512 * DMODEL);
  f32_to_f16<<<1024, blk, 0, stream>>>(v_w, wvb, 512 * DMODEL);
  f32_to_f16<<<4096, blk, 0, stream>>>(out_w, wob, DMODEL * DMODEL);

  gemm_bt<false><<<dim3(32, 16), blk, 0, stream>>>(xb, wqb, qraw, 2048, 2048);
  gemm_kv<<<dim3(32, 4, 2), blk, 0, stream>>>(xb, wkb, wvb, kraw, vraw, 512, 2048);

  postproc<<<dim3((BS * NH) / 4), blk, 0, stream>>>(qraw, qbuf, q_gain, NH, 2);
  postproc<<<dim3((BS * NKV) / 4), blk, 0, stream>>>(kraw, kbuf, q_gain, NKV, 1);
  v_transpose<<<dim3(BS / 64, 8), blk, 0, stream>>>(vraw, vT);

  attn_fwd<<<dim3(32, 2 * NH), blk, 0, stream>>>(qbuf, kbuf, vT, attn);

  gemm_bt<true><<<dim3(32, 16), blk, 0, stream>>>(attn, wob, out, 2048, 2048);
}